// Round 5
// baseline (167.727 us; speedup 1.0000x reference)
//
#include <hip/hip_runtime.h>
#include <hip/hip_bf16.h>

// HierarchicalAttention: B=4,T=50,D=512, SRC=400, SENTS=16, WORDS=40.
// 5-launch pipeline (R3 structure = proven 154.7us, + k2 4-slot waves, + k3c wave-split-K):
//   k0f  fused transposes: weights->bf16 Wt[n][k], banks->bf16 Mt[b][d][s]
//   k1   MFMA projections, depth-2 register prefetch (outputs pre-scaled by 2*log2e)
//   k2   tanh scores — 4 slots/wave (wq rows amortized 4x), scratch-free accumulators
//   k3a  hier combine + mask + softmax -> bf16 P
//   k3c  MFMA context GEMM — waves split K (barrier-free K-loop), one final reduce

#define B_    4
#define T_    50
#define D_    512
#define SRC_  400
#define SENTS_ 16
#define WORDS_ 40
#define NW_   640      // SENTS*WORDS
#define NMEM_ 1040     // SRC + NW
#define NK_   1056     // NMEM padded to 32*33 for MFMA K-loop

#define C2L2E 2.8853900817779268f   // 2*log2(e): x -> exp2(C2L2E*x) = exp(2x)

typedef unsigned short ushort_t;
using s8v = __attribute__((ext_vector_type(8))) short;   // 8 bf16 (4 VGPRs)
using f4v = __attribute__((ext_vector_type(4))) float;   // MFMA accumulator

// ---- workspace layout ----
// f32 region (float offsets):
#define OFF_WQ_WORD 0
#define OFF_WQ_SENT 102400
#define OFF_WQ_PASS 204800
#define OFF_UH_SRC  307200
#define OFF_UH_WORD 1126400
#define OFF_UH_SENT 2437120
#define OFF_SC_SRC  2469888
#define OFF_SC_WORD 2549888
#define OFF_SC_SENT 2677888
// bf16 regions (byte offsets):
#define P_BYTE_OFF  10724352ull   // P[b][64][1056]  bf16 = 540672 B
#define MT_BYTE_OFF 11265024ull   // Mt[b][512][1056] bf16 = 4325376 B
#define WT_BYTE_OFF 15590400ull   // Wt[6][512][512] bf16 = 3145728 B

__device__ __forceinline__ ushort_t f2b(float f) {
    __hip_bfloat16 h = __float2bfloat16(f);   // RNE
    return *(ushort_t*)&h;
}

// ---------------- k0f: fused transposes (compact 1D grid, 3648 blocks) ----------------
// bid < 1536: weight W[k][n] -> Wt[n][k]  (z = bid>>8, 16x16 tiles)
// bid >= 1536: banks -> Mt[b][d][s]       (4 b x 16 d-tiles x 33 s-tiles)
__global__ __launch_bounds__(256) void k0f_transpose(
    const float* __restrict__ w0, const float* __restrict__ w1,
    const float* __restrict__ w2, const float* __restrict__ w3,
    const float* __restrict__ w4, const float* __restrict__ w5,
    const float* __restrict__ src_bank, const float* __restrict__ qa_word_bank,
    ushort_t* __restrict__ wt, ushort_t* __restrict__ mt)
{
    __shared__ float tile[32][33];
    int bid = blockIdx.x;
    int tx = threadIdx.x & 31, ty = threadIdx.x >> 5;
    if (bid < 1536) {
        int z = bid >> 8, r = bid & 255;
        int n0 = (r & 15) * 32, k0 = (r >> 4) * 32;
        const float* W;
        switch (z) {
            case 0: W = w0; break; case 1: W = w1; break; case 2: W = w2; break;
            case 3: W = w3; break; case 4: W = w4; break; default: W = w5; break;
        }
        ushort_t* Wt = wt + z * (D_ * D_);
#pragma unroll
        for (int a = 0; a < 4; ++a)
            tile[ty + a * 8][tx] = W[(k0 + ty + a * 8) * D_ + n0 + tx];
        __syncthreads();
#pragma unroll
        for (int a = 0; a < 4; ++a)
            Wt[(n0 + ty + a * 8) * D_ + k0 + tx] = f2b(tile[tx][ty + a * 8]);
    } else {
        int tb = bid - 1536;
        int b = tb / 528, r = tb - b * 528;
        int s0 = (r % 33) * 32, d0 = (r / 33) * 32;
#pragma unroll
        for (int a = 0; a < 4; ++a) {
            int s = s0 + ty + a * 8;
            float val = 0.f;
            if (s < SRC_) {
                val = src_bank[(s * B_ + b) * D_ + d0 + tx];
            } else if (s < NMEM_) {
                int j = s - SRC_; int se = j / WORDS_; int wd = j - se * WORDS_;
                val = qa_word_bank[((wd * B_ + b) * SENTS_ + se) * D_ + d0 + tx];
            }
            tile[ty + a * 8][tx] = val;
        }
        __syncthreads();
        ushort_t* base = mt + (size_t)b * D_ * NK_;
#pragma unroll
        for (int a = 0; a < 4; ++a) {
            int d = d0 + ty + a * 8;
            base[(size_t)d * NK_ + s0 + tx] = f2b(tile[tx][ty + a * 8]);
        }
    }
}

// ---------------- k1: all projections via bf16 MFMA, fp32*C2L2E out to ws ----------------
// Compact 1D grid (624 blocks): z0-2: 32 blocks each (M=200), z3: 320 (M=2560),
// z4: 200 (M=1600), z5: 8 (M=64). Block tile 64x64, K=512 in 16 steps.
// Depth-2 register prefetch: A and Wt loads issued 2 steps ahead.
__global__ __launch_bounds__(256) void k1_gemm(
    const float* __restrict__ source, const float* __restrict__ src_bank,
    const float* __restrict__ qa_sent_bank, const float* __restrict__ qa_word_bank,
    const ushort_t* __restrict__ wt,
    const float* __restrict__ bq_word, const float* __restrict__ bq_sent,
    const float* __restrict__ bq_pass,
    float* __restrict__ wsf)
{
    __shared__ short At[64 * 32];
    __shared__ short Bt[64 * 32];
    int bid = blockIdx.x;
    int z, rem;
    if (bid < 96)       { z = bid >> 5; rem = bid & 31; }
    else if (bid < 416) { z = 3; rem = bid - 96; }
    else if (bid < 616) { z = 4; rem = bid - 416; }
    else                { z = 5; rem = bid - 616; }
    int by = rem >> 3, bx = rem & 7;
    int M, atype; const float* bias; float* C;
    switch (z) {
        case 0: M = 200;  atype = 0; bias = bq_word; C = wsf + OFF_WQ_WORD; break;
        case 1: M = 200;  atype = 0; bias = bq_sent; C = wsf + OFF_WQ_SENT; break;
        case 2: M = 200;  atype = 0; bias = bq_pass; C = wsf + OFF_WQ_PASS; break;
        case 3: M = 2560; atype = 1; bias = nullptr; C = wsf + OFF_UH_WORD; break;
        case 4: M = 1600; atype = 2; bias = nullptr; C = wsf + OFF_UH_SRC;  break;
        default: M = 64;  atype = 3; bias = nullptr; C = wsf + OFF_UH_SENT; break;
    }
    int m0 = by * 64, n0 = bx * 64;
    const ushort_t* W = wt + z * (D_ * D_);   // Wt: [n][k] bf16

    int tid = threadIdx.x;
    int lane = tid & 63, wv = tid >> 6;
    int quad = lane >> 4, l16 = lane & 15;
    int sm = tid >> 2, koff = (tid & 3) * 8;  // staging: row sm, 8-elem chunk koff

    // A-row gather base (row -> global f32 pointer per segment type)
    const float* arow = nullptr;
    {
        int r = m0 + sm;
        if (r < M) {
            if (atype == 0) arow = source + r * D_;
            else if (atype == 1) { int b = r / NW_; int j = r - b * NW_;
                                   int se = j / WORDS_; int wd = j - se * WORDS_;
                                   arow = qa_word_bank + ((wd * B_ + b) * SENTS_ + se) * D_; }
            else if (atype == 2) { int b = r / SRC_; int j = r - b * SRC_;
                                   arow = src_bank + (j * B_ + b) * D_; }
            else                 { int b = r >> 4; int s2 = r & 15;
                                   arow = qa_sent_bank + (s2 * B_ + b) * D_; }
        }
    }
    const ushort_t* wrow = W + (n0 + sm) * D_;

    auto loadA = [&](float* r, int kk) {
        if (arow) {
            float4 f0 = *(const float4*)(arow + kk * 32 + koff);
            float4 f1 = *(const float4*)(arow + kk * 32 + koff + 4);
            r[0]=f0.x; r[1]=f0.y; r[2]=f0.z; r[3]=f0.w;
            r[4]=f1.x; r[5]=f1.y; r[6]=f1.z; r[7]=f1.w;
        } else {
#pragma unroll
            for (int i = 0; i < 8; ++i) r[i] = 0.f;
        }
    };

    f4v acc[4] = { {0.f,0.f,0.f,0.f}, {0.f,0.f,0.f,0.f},
                   {0.f,0.f,0.f,0.f}, {0.f,0.f,0.f,0.f} };

    // depth-2 prefetch pipeline
    float a0[8], a1[8];
    int4 w0v, w1v;
    loadA(a0, 0); w0v = *(const int4*)(wrow + 0 * 32 + koff);
    loadA(a1, 1); w1v = *(const int4*)(wrow + 1 * 32 + koff);

    for (int kk = 0; kk < 16; ++kk) {
        // store current tiles to LDS
        union { ushort_t u[8]; int4 v; } pk;
#pragma unroll
        for (int i = 0; i < 8; ++i) pk.u[i] = f2b(a0[i]);
        *(int4*)(At + sm * 32 + koff) = pk.v;
        *(int4*)(Bt + sm * 32 + koff) = w0v;
        __syncthreads();
        // rotate + prefetch kk+2 (lands by the time it is stored, ~2 iters later)
#pragma unroll
        for (int i = 0; i < 8; ++i) a0[i] = a1[i];
        w0v = w1v;
        if (kk < 14) {
            loadA(a1, kk + 2);
            w1v = *(const int4*)(wrow + (kk + 2) * 32 + koff);
        }
        s8v af = *(const s8v*)(At + (wv * 16 + l16) * 32 + quad * 8);
#pragma unroll
        for (int ng = 0; ng < 4; ++ng) {
            s8v bf = *(const s8v*)(Bt + (ng * 16 + l16) * 32 + quad * 8);
            acc[ng] = __builtin_amdgcn_mfma_f32_16x16x32_bf16(af, bf, acc[ng], 0, 0, 0);
        }
        __syncthreads();
    }
    // epilogue: D col = lane&15, row = quad*4 + r. Pre-scale by 2*log2e so
    // k2 can use exp2 directly: stored value = (acc+bias) * C2L2E.
#pragma unroll
    for (int ng = 0; ng < 4; ++ng) {
        int col = n0 + ng * 16 + l16;
        float bb = bias ? bias[col] : 0.f;
#pragma unroll
        for (int rr = 0; rr < 4; ++rr) {
            int row = m0 + wv * 16 + quad * 4 + rr;
            if (row < M) C[row * D_ + col] = (acc[ng][rr] + bb) * C2L2E;
        }
    }
}

// ---------------- k2: additive-attention scores — 4 slots per wave ----------------
// 528 blocks x 4 waves = 2112 wave-jobs: (b, half, group-of-4-slots). Each wave
// holds 4 uh rows in registers and streams 25 wq rows, using each for all 4
// slots (4x fewer wq reads, 4x fewer waves). Groups never cross segment or
// sentence boundaries (400%4==0, 40%4==0, 16%4==0); fully-masked groups exit
// (contiguous mask => slot0>=len implies all masked); per-slot guard at store.
// score = Vsum - 2*sum_d v[d]*sigmoid(-2x); exp(2x)=exp2(pre-scaled sum).
// All accumulator indices static (no local-memory scratch).
__global__ __launch_bounds__(256) void k2_scores(
    const float* __restrict__ v_word, const float* __restrict__ v_sent,
    const float* __restrict__ v_pass,
    const int* __restrict__ src_lengths, const int* __restrict__ qa_word_lengths,
    float* __restrict__ wsf)
{
    int lane = threadIdx.x & 63;
    int jid = blockIdx.x * 4 + (threadIdx.x >> 6);   // 2112 wave-jobs, exact
    int b = jid / 528, r = jid - b * 528;
    int th = r & 1, grp = r >> 1;                    // grp in [0,264)
    const float* uhb; const float* v; const float* wq; float* outb; int ostride;
    int nact;
    if (grp < 100) {
        int slot0 = grp * 4;
        int slen = src_lengths[b];
        if (slot0 >= slen) return;                   // whole group masked
        nact = min(4, slen - slot0);
        uhb = wsf + OFF_UH_SRC + (size_t)(b * SRC_ + slot0) * D_;
        v = v_pass; wq = wsf + OFF_WQ_PASS + b * T_ * D_;
        outb = wsf + OFF_SC_SRC + b * T_ * SRC_ + slot0; ostride = SRC_;
    } else if (grp < 260) {
        int g = grp - 100; int se = g / 10; int wd0 = (g - se * 10) * 4;
        int lim = qa_word_lengths[b * SENTS_ + se];
        if (wd0 >= lim) return;                      // whole group masked
        nact = min(4, lim - wd0);
        int jw = se * WORDS_ + wd0;
        uhb = wsf + OFF_UH_WORD + (size_t)(b * NW_ + jw) * D_;
        v = v_word; wq = wsf + OFF_WQ_WORD + b * T_ * D_;
        outb = wsf + OFF_SC_WORD + b * T_ * NW_ + jw; ostride = NW_;
    } else {
        int s0 = (grp - 260) * 4;
        nact = 4;                                    // sentences unmasked
        uhb = wsf + OFF_UH_SENT + (size_t)(b * SENTS_ + s0) * D_;
        v = v_sent; wq = wsf + OFF_WQ_SENT + b * T_ * D_;
        outb = wsf + OFF_SC_SENT + b * T_ * SENTS_ + s0; ostride = SENTS_;
    }
    int d0 = lane * 8;

    // 4 uh rows + v row into registers (all rows exist regardless of masks)
    float uhr[4][8];
#pragma unroll
    for (int u = 0; u < 4; ++u) {
        float4 f0 = *(const float4*)(uhb + u * D_ + d0);
        float4 f1 = *(const float4*)(uhb + u * D_ + d0 + 4);
        uhr[u][0]=f0.x; uhr[u][1]=f0.y; uhr[u][2]=f0.z; uhr[u][3]=f0.w;
        uhr[u][4]=f1.x; uhr[u][5]=f1.y; uhr[u][6]=f1.z; uhr[u][7]=f1.w;
    }
    float4 v0 = *(const float4*)(v + d0);
    float4 v1 = *(const float4*)(v + d0 + 4);
    float vr[8] = {v0.x, v0.y, v0.z, v0.w, v1.x, v1.y, v1.z, v1.w};

    // Vsum = sum_d v[d] (broadcast)
    float vs = ((vr[0] + vr[1]) + (vr[2] + vr[3])) + ((vr[4] + vr[5]) + (vr[6] + vr[7]));
#pragma unroll
    for (int off = 32; off > 0; off >>= 1) vs += __shfl_xor(vs, off, 64);

    const float* wqh = wq + th * 25 * D_ + d0;
#pragma unroll 1
    for (int g = 0; g < 5; ++g) {
        float a[4][5];   // [slot][t5] — all indices static under full unroll
#pragma unroll
        for (int t5 = 0; t5 < 5; ++t5) {
            const float* wr = wqh + (g * 5 + t5) * D_;
            float4 w0 = *(const float4*)(wr);
            float4 w1 = *(const float4*)(wr + 4);
            float wrr[8] = {w0.x, w0.y, w0.z, w0.w, w1.x, w1.y, w1.z, w1.w};
#pragma unroll
            for (int u = 0; u < 4; ++u) {
                float acc = 0.f;
#pragma unroll
                for (int j = 0; j < 8; ++j) {
                    float e = __builtin_amdgcn_exp2f(wrr[j] + uhr[u][j]);  // exp(2x)
                    float rc = __builtin_amdgcn_rcpf(e + 1.f);             // sigmoid(-2x)
                    acc = fmaf(vr[j], rc, acc);
                }
                a[u][t5] = acc;
            }
        }
        // 20 interleaved butterfly reductions
#pragma unroll
        for (int off = 32; off > 0; off >>= 1) {
#pragma unroll
            for (int u = 0; u < 4; ++u)
#pragma unroll
                for (int t5 = 0; t5 < 5; ++t5)
                    a[u][t5] += __shfl_xor(a[u][t5], off, 64);
        }
        if (lane == 0) {
#pragma unroll
            for (int t5 = 0; t5 < 5; ++t5) {
                int trow = (th * 25 + g * 5 + t5) * ostride;
#pragma unroll
                for (int u = 0; u < 4; ++u)
                    if (u < nact) outb[trow + u] = fmaf(-2.f, a[u][t5], vs);
            }
        }
    }
}

// ---------------- k3a: hier combine + mask + softmax -> bf16 P[b][64][1056] ----------------
__global__ __launch_bounds__(256) void k3a_softmax(
    const int* __restrict__ src_lengths, const int* __restrict__ qa_word_lengths,
    const float* __restrict__ wsf, ushort_t* __restrict__ P)
{
    __shared__ float p[NMEM_];
    __shared__ float red[4];
    int tid = threadIdx.x, lane = tid & 63, wv = tid >> 6;
    int bt = blockIdx.x, b = bt / T_, t = bt - b * T_;
    const float* sc_src  = wsf + OFF_SC_SRC  + bt * SRC_;
    const float* sc_word = wsf + OFF_SC_WORD + bt * NW_;
    const float* sc_sent = wsf + OFF_SC_SENT + bt * SENTS_;
    int slen = src_lengths[b];
    float mx = -3.0e38f;
    for (int j = tid; j < NMEM_; j += 256) {
        float val;
        if (j < SRC_) {
            val = (j < slen) ? sc_src[j] : -1e30f;
        } else {
            int jj = j - SRC_; int se = jj / WORDS_; int wd = jj - se * WORDS_;
            float raw = sc_word[jj] * sc_sent[se];
            val = (wd < qa_word_lengths[b * SENTS_ + se]) ? raw : -1e30f;
        }
        p[j] = val;
        mx = fmaxf(mx, val);
    }
#pragma unroll
    for (int off = 32; off > 0; off >>= 1) mx = fmaxf(mx, __shfl_xor(mx, off, 64));
    if (lane == 0) red[wv] = mx;
    __syncthreads();
    mx = fmaxf(fmaxf(red[0], red[1]), fmaxf(red[2], red[3]));
    __syncthreads();
    float lsum = 0.f;
    for (int j = tid; j < NMEM_; j += 256) {
        float e = __expf(p[j] - mx);
        p[j] = e; lsum += e;
    }
#pragma unroll
    for (int off = 32; off > 0; off >>= 1) lsum += __shfl_xor(lsum, off, 64);
    if (lane == 0) red[wv] = lsum;
    __syncthreads();
    float inv = 1.f / (red[0] + red[1] + red[2] + red[3]);
    ushort_t* prow = P + (size_t)(b * 64 + t) * NK_;
    for (int j = tid; j < NK_; j += 256)
        prow[j] = (j < NMEM_) ? f2b(p[j] * inv) : (ushort_t)0;
}

// ---------------- k3c: context GEMM  C[b][t][d] = sum_s P[t,s] * Mt[d,s] ----------------
// grid (16 d-tiles, 4 b), 256 thr. Waves split K (9/8/8/8 of 33 k-steps), each
// staging into a PRIVATE LDS region — no barrier in the K-loop (same-wave LDS
// RAW is ordered). Depth-1 register prefetch. One __syncthreads, then a
// cross-wave partial-sum reduce and the f32 store.
__global__ __launch_bounds__(256) void k3c_gemm(
    const ushort_t* __restrict__ P, const ushort_t* __restrict__ Mt,
    float* __restrict__ out)
{
    __shared__ short AtW[4][64 * 32];    // per-wave A tile (4 KB each)
    __shared__ short BtW[4][32 * 32];    // per-wave B tile (2 KB each)
    __shared__ float Cred[4][64 * 32];   // per-wave partial C (8 KB each)
    int b = blockIdx.y;
    int n0 = blockIdx.x * 32;
    int tid = threadIdx.x;
    int lane = tid & 63, w = tid >> 6;
    int quad = lane >> 4, l16 = lane & 15;

    int ks = (w == 0) ? 0 : 9 + (w - 1) * 8;
    int ke = ks + ((w == 0) ? 9 : 8);

    // staging roles: lane stages A row=lane (32 shorts = 4 int4),
    // B row=lane>>1, half=(lane&1)*16 (16 shorts = 2 int4)
    const ushort_t* arow = P + (size_t)(b * 64 + lane) * NK_;
    const ushort_t* brow = Mt + (size_t)(b * D_ + n0 + (lane >> 1)) * NK_ + (lane & 1) * 16;
    short* At = AtW[w];
    short* Bt = BtW[w];
    short* atd = At + lane * 32;
    short* btd = Bt + (lane >> 1) * 32 + (lane & 1) * 16;

    f4v acc[4][2];
#pragma unroll
    for (int mi = 0; mi < 4; ++mi)
#pragma unroll
        for (int ng = 0; ng < 2; ++ng) acc[mi][ng] = f4v{0.f, 0.f, 0.f, 0.f};

    // depth-1 prefetch of step ks
    int4 pa0 = *(const int4*)(arow + ks * 32);
    int4 pa1 = *(const int4*)(arow + ks * 32 + 8);
    int4 pa2 = *(const int4*)(arow + ks * 32 + 16);
    int4 pa3 = *(const int4*)(arow + ks * 32 + 24);
    int4 pb0 = *(const int4*)(brow + ks * 32);
    int4 pb1 = *(const int4*)(brow + ks * 32 + 8);

    for (int kk = ks; kk < ke; ++kk) {
        *(int4*)(atd)      = pa0;
        *(int4*)(atd + 8)  = pa1;
        *(int4*)(atd + 16) = pa2;
        *(int4*)(atd + 24) = pa3;
        *(int4*)(btd)      = pb0;
        *(int4*)(btd + 8)  = pb1;
        if (kk + 1 < ke) {
            pa0 = *(const int4*)(arow + (kk + 1) * 32);
            pa1 = *(const int4*)(arow + (kk + 1) * 32 + 8);
            pa2 = *(const int4*)(arow + (kk + 1) * 32 + 16);
            pa3 = *(const int4*)(arow + (kk + 1) * 32 + 24);
            pb0 = *(const int4*)(brow + (kk + 1) * 32);
            pb1 = *(const int4*)(brow + (kk + 1) * 32 + 8);
        }
        // compiler orders ds_read after the aliasing ds_write (same-wave RAW)
#pragma unroll
        for (int mi = 0; mi < 4; ++mi) {
            s8v af = *(const s8v*)(At + (mi * 16 + l16) * 32 + quad * 8);
#pragma unroll
            for (int ng = 0; ng < 2; ++ng) {
                s8v bf = *(const s8v*)(Bt + (ng * 16 + l16) * 32 + quad * 8);
                acc[mi][ng] = __builtin_amdgcn_mfma_f32_16x16x32_bf16(af, bf, acc[mi][ng], 0, 0, 0);
            }
        }
    }

    // write per-wave partials: row = mi*16+quad*4+rr, col = ng*16+l16
#pragma unroll
    for (int mi = 0; mi < 4; ++mi)
#pragma unroll
        for (int ng = 0; ng < 2; ++ng)
#pragma unroll
            for (int rr = 0; rr < 4; ++rr)
                Cred[w][(mi * 16 + quad * 4 + rr) * 32 + ng * 16 + l16] = acc[mi][ng][rr];
    __syncthreads();

    // cross-wave reduce + store: 2048 positions / 256 threads = 8 each (consecutive)
    int i0 = tid * 8;
#pragma unroll
    for (int e = 0; e < 8; ++e) {
        int idx = i0 + e;
        int row = idx >> 5, col = idx & 31;
        float s = ((Cred[0][idx] + Cred[1][idx]) + (Cred[2][idx] + Cred[3][idx]));
        if (row < T_) out[(size_t)(b * T_ + row) * D_ + n0 + col] = s;
    }
}

extern "C" void kernel_launch(void* const* d_in, const int* in_sizes, int n_in,
                              void* d_out, int out_size, void* d_ws, size_t ws_size,
                              hipStream_t stream)
{
    (void)in_sizes; (void)n_in; (void)out_size; (void)ws_size;
    const float* source          = (const float*)d_in[0];
    const float* src_bank        = (const float*)d_in[1];
    const int*   src_lengths     = (const int*)d_in[2];
    const float* qa_sent_bank    = (const float*)d_in[3];
    /* d_in[4] qa_sent_lengths unused (matches reference) */
    const float* qa_word_bank    = (const float*)d_in[5];
    const int*   qa_word_lengths = (const int*)d_in[6];
    const float* Wq_word = (const float*)d_in[7];
    const float* bq_word = (const float*)d_in[8];
    const float* Uc_word = (const float*)d_in[9];
    const float* v_word  = (const float*)d_in[10];
    const float* Wq_sent = (const float*)d_in[11];
    const float* bq_sent = (const float*)d_in[12];
    const float* Uc_sent = (const float*)d_in[13];
    const float* v_sent  = (const float*)d_in[14];
    const float* Wq_pass = (const float*)d_in[15];
    const float* bq_pass = (const float*)d_in[16];
    const float* Uc_pass = (const float*)d_in[17];
    const float* v_pass  = (const float*)d_in[18];

    float* wsf = (float*)d_ws;
    ushort_t* Pb  = (ushort_t*)((char*)d_ws + P_BYTE_OFF);
    ushort_t* mt  = (ushort_t*)((char*)d_ws + MT_BYTE_OFF);
    ushort_t* wt  = (ushort_t*)((char*)d_ws + WT_BYTE_OFF);
    float* out = (float*)d_out;

    // Wt slot order must match k1 segment order:
    // 0:Wq_word 1:Wq_sent 2:Wq_pass 3:Uc_word 4:Uc_pass 5:Uc_sent
    k0f_transpose<<<dim3(3648), dim3(256), 0, stream>>>(
        Wq_word, Wq_sent, Wq_pass, Uc_word, Uc_pass, Uc_sent,
        src_bank, qa_word_bank, wt, mt);
    k1_gemm<<<dim3(624), dim3(256), 0, stream>>>(
        source, src_bank, qa_sent_bank, qa_word_bank, wt,
        bq_word, bq_sent, bq_pass, wsf);
    k2_scores<<<dim3(528), dim3(256), 0, stream>>>(
        v_word, v_sent, v_pass, src_lengths, qa_word_lengths, wsf);
    k3a_softmax<<<dim3(200), dim3(256), 0, stream>>>(src_lengths, qa_word_lengths, wsf, Pb);
    k3c_gemm<<<dim3(16, 4), dim3(256), 0, stream>>>(Pb, mt, out);
}

// Round 7
// 153.331 us; speedup vs baseline: 1.0939x; 1.0939x over previous
//
#include <hip/hip_runtime.h>
#include <hip/hip_bf16.h>

// HierarchicalAttention: B=4,T=50,D=512, SRC=400, SENTS=16, WORDS=40.
// 5-launch pipeline (R3 structure = proven 154.7us; k2 re-split for max TLP):
//   k0f  fused transposes: weights->bf16 Wt[n][k], banks->bf16 Mt[b][d][s]
//   k1   MFMA projections, depth-2 register prefetch (outputs pre-scaled by 2*log2e)
//   k2   tanh scores — 5 wave-fifths per (b,slot), 10 t-rows each (21120 waves;
//        score phase is latency-bound and scales with wave count — R4/R5 evidence)
//   k3a  hier combine + mask + softmax -> bf16 P
//   k3c  MFMA context GEMM, depth-3 register prefetch (P x M -> out)

#define B_    4
#define T_    50
#define D_    512
#define SRC_  400
#define SENTS_ 16
#define WORDS_ 40
#define NW_   640      // SENTS*WORDS
#define NMEM_ 1040     // SRC + NW
#define NK_   1056     // NMEM padded to 32*33 for MFMA K-loop
#define NJOB_ 1056     // NMEM + SENTS (score jobs per batch)

#define C2L2E 2.8853900817779268f   // 2*log2(e): x -> exp2(C2L2E*x) = exp(2x)

typedef unsigned short ushort_t;
using s8v = __attribute__((ext_vector_type(8))) short;   // 8 bf16 (4 VGPRs)
using f4v = __attribute__((ext_vector_type(4))) float;   // MFMA accumulator

// ---- workspace layout ----
// f32 region (float offsets):
#define OFF_WQ_WORD 0
#define OFF_WQ_SENT 102400
#define OFF_WQ_PASS 204800
#define OFF_UH_SRC  307200
#define OFF_UH_WORD 1126400
#define OFF_UH_SENT 2437120
#define OFF_SC_SRC  2469888
#define OFF_SC_WORD 2549888
#define OFF_SC_SENT 2677888
// bf16 regions (byte offsets):
#define P_BYTE_OFF  10724352ull   // P[b][64][1056]  bf16 = 540672 B
#define MT_BYTE_OFF 11265024ull   // Mt[b][512][1056] bf16 = 4325376 B
#define WT_BYTE_OFF 15590400ull   // Wt[6][512][512] bf16 = 3145728 B

__device__ __forceinline__ ushort_t f2b(float f) {
    __hip_bfloat16 h = __float2bfloat16(f);   // RNE
    return *(ushort_t*)&h;
}

// ---------------- k0f: fused transposes (compact 1D grid, 3648 blocks) ----------------
// bid < 1536: weight W[k][n] -> Wt[n][k]  (z = bid>>8, 16x16 tiles)
// bid >= 1536: banks -> Mt[b][d][s]       (4 b x 16 d-tiles x 33 s-tiles)
__global__ __launch_bounds__(256) void k0f_transpose(
    const float* __restrict__ w0, const float* __restrict__ w1,
    const float* __restrict__ w2, const float* __restrict__ w3,
    const float* __restrict__ w4, const float* __restrict__ w5,
    const float* __restrict__ src_bank, const float* __restrict__ qa_word_bank,
    ushort_t* __restrict__ wt, ushort_t* __restrict__ mt)
{
    __shared__ float tile[32][33];
    int bid = blockIdx.x;
    int tx = threadIdx.x & 31, ty = threadIdx.x >> 5;
    if (bid < 1536) {
        int z = bid >> 8, r = bid & 255;
        int n0 = (r & 15) * 32, k0 = (r >> 4) * 32;
        const float* W;
        switch (z) {
            case 0: W = w0; break; case 1: W = w1; break; case 2: W = w2; break;
            case 3: W = w3; break; case 4: W = w4; break; default: W = w5; break;
        }
        ushort_t* Wt = wt + z * (D_ * D_);
#pragma unroll
        for (int a = 0; a < 4; ++a)
            tile[ty + a * 8][tx] = W[(k0 + ty + a * 8) * D_ + n0 + tx];
        __syncthreads();
#pragma unroll
        for (int a = 0; a < 4; ++a)
            Wt[(n0 + ty + a * 8) * D_ + k0 + tx] = f2b(tile[tx][ty + a * 8]);
    } else {
        int tb = bid - 1536;
        int b = tb / 528, r = tb - b * 528;
        int s0 = (r % 33) * 32, d0 = (r / 33) * 32;
#pragma unroll
        for (int a = 0; a < 4; ++a) {
            int s = s0 + ty + a * 8;
            float val = 0.f;
            if (s < SRC_) {
                val = src_bank[(s * B_ + b) * D_ + d0 + tx];
            } else if (s < NMEM_) {
                int j = s - SRC_; int se = j / WORDS_; int wd = j - se * WORDS_;
                val = qa_word_bank[((wd * B_ + b) * SENTS_ + se) * D_ + d0 + tx];
            }
            tile[ty + a * 8][tx] = val;
        }
        __syncthreads();
        ushort_t* base = mt + (size_t)b * D_ * NK_;
#pragma unroll
        for (int a = 0; a < 4; ++a) {
            int d = d0 + ty + a * 8;
            base[(size_t)d * NK_ + s0 + tx] = f2b(tile[tx][ty + a * 8]);
        }
    }
}

// ---------------- k1: all projections via bf16 MFMA, fp32*C2L2E out to ws ----------------
// Compact 1D grid (624 blocks): z0-2: 32 blocks each (M=200), z3: 320 (M=2560),
// z4: 200 (M=1600), z5: 8 (M=64). Block tile 64x64, K=512 in 16 steps.
// Depth-2 register prefetch: A and Wt loads issued 2 steps ahead.
__global__ __launch_bounds__(256) void k1_gemm(
    const float* __restrict__ source, const float* __restrict__ src_bank,
    const float* __restrict__ qa_sent_bank, const float* __restrict__ qa_word_bank,
    const ushort_t* __restrict__ wt,
    const float* __restrict__ bq_word, const float* __restrict__ bq_sent,
    const float* __restrict__ bq_pass,
    float* __restrict__ wsf)
{
    __shared__ short At[64 * 32];
    __shared__ short Bt[64 * 32];
    int bid = blockIdx.x;
    int z, rem;
    if (bid < 96)       { z = bid >> 5; rem = bid & 31; }
    else if (bid < 416) { z = 3; rem = bid - 96; }
    else if (bid < 616) { z = 4; rem = bid - 416; }
    else                { z = 5; rem = bid - 616; }
    int by = rem >> 3, bx = rem & 7;
    int M, atype; const float* bias; float* C;
    switch (z) {
        case 0: M = 200;  atype = 0; bias = bq_word; C = wsf + OFF_WQ_WORD; break;
        case 1: M = 200;  atype = 0; bias = bq_sent; C = wsf + OFF_WQ_SENT; break;
        case 2: M = 200;  atype = 0; bias = bq_pass; C = wsf + OFF_WQ_PASS; break;
        case 3: M = 2560; atype = 1; bias = nullptr; C = wsf + OFF_UH_WORD; break;
        case 4: M = 1600; atype = 2; bias = nullptr; C = wsf + OFF_UH_SRC;  break;
        default: M = 64;  atype = 3; bias = nullptr; C = wsf + OFF_UH_SENT; break;
    }
    int m0 = by * 64, n0 = bx * 64;
    const ushort_t* W = wt + z * (D_ * D_);   // Wt: [n][k] bf16

    int tid = threadIdx.x;
    int lane = tid & 63, wv = tid >> 6;
    int quad = lane >> 4, l16 = lane & 15;
    int sm = tid >> 2, koff = (tid & 3) * 8;  // staging: row sm, 8-elem chunk koff

    // A-row gather base (row -> global f32 pointer per segment type)
    const float* arow = nullptr;
    {
        int r = m0 + sm;
        if (r < M) {
            if (atype == 0) arow = source + r * D_;
            else if (atype == 1) { int b = r / NW_; int j = r - b * NW_;
                                   int se = j / WORDS_; int wd = j - se * WORDS_;
                                   arow = qa_word_bank + ((wd * B_ + b) * SENTS_ + se) * D_; }
            else if (atype == 2) { int b = r / SRC_; int j = r - b * SRC_;
                                   arow = src_bank + (j * B_ + b) * D_; }
            else                 { int b = r >> 4; int s2 = r & 15;
                                   arow = qa_sent_bank + (s2 * B_ + b) * D_; }
        }
    }
    const ushort_t* wrow = W + (n0 + sm) * D_;

    auto loadA = [&](float* r, int kk) {
        if (arow) {
            float4 f0 = *(const float4*)(arow + kk * 32 + koff);
            float4 f1 = *(const float4*)(arow + kk * 32 + koff + 4);
            r[0]=f0.x; r[1]=f0.y; r[2]=f0.z; r[3]=f0.w;
            r[4]=f1.x; r[5]=f1.y; r[6]=f1.z; r[7]=f1.w;
        } else {
#pragma unroll
            for (int i = 0; i < 8; ++i) r[i] = 0.f;
        }
    };

    f4v acc[4] = { {0.f,0.f,0.f,0.f}, {0.f,0.f,0.f,0.f},
                   {0.f,0.f,0.f,0.f}, {0.f,0.f,0.f,0.f} };

    // depth-2 prefetch pipeline
    float a0[8], a1[8];
    int4 w0v, w1v;
    loadA(a0, 0); w0v = *(const int4*)(wrow + 0 * 32 + koff);
    loadA(a1, 1); w1v = *(const int4*)(wrow + 1 * 32 + koff);

    for (int kk = 0; kk < 16; ++kk) {
        // store current tiles to LDS
        union { ushort_t u[8]; int4 v; } pk;
#pragma unroll
        for (int i = 0; i < 8; ++i) pk.u[i] = f2b(a0[i]);
        *(int4*)(At + sm * 32 + koff) = pk.v;
        *(int4*)(Bt + sm * 32 + koff) = w0v;
        __syncthreads();
        // rotate + prefetch kk+2 (lands by the time it is stored, ~2 iters later)
#pragma unroll
        for (int i = 0; i < 8; ++i) a0[i] = a1[i];
        w0v = w1v;
        if (kk < 14) {
            loadA(a1, kk + 2);
            w1v = *(const int4*)(wrow + (kk + 2) * 32 + koff);
        }
        s8v af = *(const s8v*)(At + (wv * 16 + l16) * 32 + quad * 8);
#pragma unroll
        for (int ng = 0; ng < 4; ++ng) {
            s8v bf = *(const s8v*)(Bt + (ng * 16 + l16) * 32 + quad * 8);
            acc[ng] = __builtin_amdgcn_mfma_f32_16x16x32_bf16(af, bf, acc[ng], 0, 0, 0);
        }
        __syncthreads();
    }
    // epilogue: D col = lane&15, row = quad*4 + r. Pre-scale by 2*log2e so
    // k2 can use exp2 directly: stored value = (acc+bias) * C2L2E.
#pragma unroll
    for (int ng = 0; ng < 4; ++ng) {
        int col = n0 + ng * 16 + l16;
        float bb = bias ? bias[col] : 0.f;
#pragma unroll
        for (int rr = 0; rr < 4; ++rr) {
            int row = m0 + wv * 16 + quad * 4 + rr;
            if (row < M) C[row * D_ + col] = (acc[ng][rr] + bb) * C2L2E;
        }
    }
}

// ---------------- k2: additive-attention scores — 5 wave-fifths per job ----------------
// 5280 blocks x 4 waves = 21120 wave-fifths: (b, slot, fifth-of-t). Each active
// wave computes 10 t-rows for one slot (2 groups of 5 statically-indexed
// accumulators — no local-memory scratch). Masked jobs exit immediately.
// Score phase is LATENCY-bound (R5 counters: VALUBusy 25%, Occ 7% at 2112
// waves) — maximize wave count, not per-wave reuse.
// score = Vsum - 2*sum_d v[d]*sigmoid(-2x); exp(2x)=exp2(pre-scaled sum).
__global__ __launch_bounds__(256) void k2_scores(
    const float* __restrict__ v_word, const float* __restrict__ v_sent,
    const float* __restrict__ v_pass,
    const int* __restrict__ src_lengths, const int* __restrict__ qa_word_lengths,
    float* __restrict__ wsf)
{
    int lane = threadIdx.x & 63;
    int jid = blockIdx.x * 4 + (threadIdx.x >> 6);   // 21120 wave-fifths, exact
    int job = jid / 5, fifth = jid - job * 5;
    int b = job / NJOB_, slot = job - b * NJOB_;
    const float* uh; const float* v; const float* wq; float* out; int ostride;
    if (slot < SRC_) {
        if (slot >= src_lengths[b]) return;           // masked: value never read
        uh = wsf + OFF_UH_SRC + (size_t)(b * SRC_ + slot) * D_;
        v = v_pass; wq = wsf + OFF_WQ_PASS + b * T_ * D_;
        out = wsf + OFF_SC_SRC + b * T_ * SRC_ + slot; ostride = SRC_;
    } else if (slot < NMEM_) {
        int j = slot - SRC_;
        int se = j / WORDS_; int wd = j - se * WORDS_;
        if (wd >= qa_word_lengths[b * SENTS_ + se]) return;  // masked
        uh = wsf + OFF_UH_WORD + (size_t)(b * NW_ + j) * D_;
        v = v_word; wq = wsf + OFF_WQ_WORD + b * T_ * D_;
        out = wsf + OFF_SC_WORD + b * T_ * NW_ + j; ostride = NW_;
    } else {
        int s2 = slot - NMEM_;
        uh = wsf + OFF_UH_SENT + (size_t)(b * SENTS_ + s2) * D_;
        v = v_sent; wq = wsf + OFF_WQ_SENT + b * T_ * D_;
        out = wsf + OFF_SC_SENT + b * T_ * SENTS_ + s2; ostride = SENTS_;
    }
    int d0 = lane * 8;
    float4 u0 = *(const float4*)(uh + d0);
    float4 u1 = *(const float4*)(uh + d0 + 4);
    float uhr[8] = {u0.x, u0.y, u0.z, u0.w, u1.x, u1.y, u1.z, u1.w};
    float4 v0 = *(const float4*)(v + d0);
    float4 v1 = *(const float4*)(v + d0 + 4);
    float vr[8] = {v0.x, v0.y, v0.z, v0.w, v1.x, v1.y, v1.z, v1.w};

    // Vsum = sum_d v[d] (broadcast to all lanes)
    float vs = ((vr[0] + vr[1]) + (vr[2] + vr[3])) + ((vr[4] + vr[5]) + (vr[6] + vr[7]));
#pragma unroll
    for (int off = 32; off > 0; off >>= 1) vs += __shfl_xor(vs, off, 64);

    const float* wqh = wq + (fifth * 10) * D_ + d0;
    int tbase = fifth * 10;
#pragma unroll 1
    for (int g = 0; g < 2; ++g) {
        float a5[5];
#pragma unroll
        for (int u5 = 0; u5 < 5; ++u5) {
            const float* wr = wqh + (g * 5 + u5) * D_;
            float4 w0 = *(const float4*)(wr);
            float4 w1 = *(const float4*)(wr + 4);
            float wrr[8] = {w0.x, w0.y, w0.z, w0.w, w1.x, w1.y, w1.z, w1.w};
            float a = 0.f;
#pragma unroll
            for (int j = 0; j < 8; ++j) {
                float e = __builtin_amdgcn_exp2f(wrr[j] + uhr[j]);  // exp(2x)
                float r = __builtin_amdgcn_rcpf(e + 1.f);           // sigmoid(-2x)
                a = fmaf(vr[j], r, a);
            }
            a5[u5] = a;
        }
        // 5 interleaved butterfly reductions (all indices static -> registers)
#pragma unroll
        for (int off = 32; off > 0; off >>= 1) {
#pragma unroll
            for (int u5 = 0; u5 < 5; ++u5) a5[u5] += __shfl_xor(a5[u5], off, 64);
        }
        if (lane == 0) {
#pragma unroll
            for (int u5 = 0; u5 < 5; ++u5)
                out[(tbase + g * 5 + u5) * ostride] = fmaf(-2.f, a5[u5], vs);
        }
    }
}

// ---------------- k3a: hier combine + mask + softmax -> bf16 P[b][64][1056] ----------------
__global__ __launch_bounds__(256) void k3a_softmax(
    const int* __restrict__ src_lengths, const int* __restrict__ qa_word_lengths,
    const float* __restrict__ wsf, ushort_t* __restrict__ P)
{
    __shared__ float p[NMEM_];
    __shared__ float red[4];
    int tid = threadIdx.x, lane = tid & 63, wv = tid >> 6;
    int bt = blockIdx.x, b = bt / T_, t = bt - b * T_;
    const float* sc_src  = wsf + OFF_SC_SRC  + bt * SRC_;
    const float* sc_word = wsf + OFF_SC_WORD + bt * NW_;
    const float* sc_sent = wsf + OFF_SC_SENT + bt * SENTS_;
    int slen = src_lengths[b];
    float mx = -3.0e38f;
    for (int j = tid; j < NMEM_; j += 256) {
        float val;
        if (j < SRC_) {
            val = (j < slen) ? sc_src[j] : -1e30f;
        } else {
            int jj = j - SRC_; int se = jj / WORDS_; int wd = jj - se * WORDS_;
            float raw = sc_word[jj] * sc_sent[se];
            val = (wd < qa_word_lengths[b * SENTS_ + se]) ? raw : -1e30f;
        }
        p[j] = val;
        mx = fmaxf(mx, val);
    }
#pragma unroll
    for (int off = 32; off > 0; off >>= 1) mx = fmaxf(mx, __shfl_xor(mx, off, 64));
    if (lane == 0) red[wv] = mx;
    __syncthreads();
    mx = fmaxf(fmaxf(red[0], red[1]), fmaxf(red[2], red[3]));
    __syncthreads();
    float lsum = 0.f;
    for (int j = tid; j < NMEM_; j += 256) {
        float e = __expf(p[j] - mx);
        p[j] = e; lsum += e;
    }
#pragma unroll
    for (int off = 32; off > 0; off >>= 1) lsum += __shfl_xor(lsum, off, 64);
    if (lane == 0) red[wv] = lsum;
    __syncthreads();
    float inv = 1.f / (red[0] + red[1] + red[2] + red[3]);
    ushort_t* prow = P + (size_t)(b * 64 + t) * NK_;
    for (int j = tid; j < NK_; j += 256)
        prow[j] = (j < NMEM_) ? f2b(p[j] * inv) : (ushort_t)0;
}

// ---------------- k3c: context GEMM  C[b][t][d] = sum_s P[t,s] * Mt[d,s] ----------------
// grid (16 d-tiles, 4 b), 256 thr. Tile 64(t,pad) x 32(d), K=1056.
// Depth-3 register prefetch of P (int4) and Mt (int2) keeps the K-loop body a
// pure copy + MFMA — no exposed global latency despite only 4 waves/block.
__global__ __launch_bounds__(256) void k3c_gemm(
    const ushort_t* __restrict__ P, const ushort_t* __restrict__ Mt,
    float* __restrict__ out)
{
    __shared__ short At[64 * 32];
    __shared__ short Bt[32 * 32];
    int b = blockIdx.y;
    int n0 = blockIdx.x * 32;
    int tid = threadIdx.x;
    int lane = tid & 63, wv = tid >> 6;
    int quad = lane >> 4, l16 = lane & 15;
    int smA = tid >> 2, koffA = (tid & 3) * 8;   // A: 64 rows x 32k, int4/thread
    int smB = tid >> 3, koffB = (tid & 7) * 4;   // B: 32 rows x 32k, int2/thread

    const ushort_t* arow = P + (size_t)(b * 64 + smA) * NK_ + koffA;
    const ushort_t* brow = Mt + ((size_t)(b * D_ + n0 + smB)) * NK_ + koffB;

    f4v acc[2] = { {0.f,0.f,0.f,0.f}, {0.f,0.f,0.f,0.f} };

    // depth-3 prefetch pipeline (invariant entering kk: a0=k(kk), a1=k(kk+1), a2=k(kk+2))
    int4 a0 = *(const int4*)(arow);
    int2 b0 = *(const int2*)(brow);
    int4 a1 = *(const int4*)(arow + 32);
    int2 b1 = *(const int2*)(brow + 32);
    int4 a2 = *(const int4*)(arow + 64);
    int2 b2 = *(const int2*)(brow + 64);

    for (int kk = 0; kk < 33; ++kk) {
        *(int4*)(At + smA * 32 + koffA) = a0;
        *(int2*)(Bt + smB * 32 + koffB) = b0;
        __syncthreads();
        a0 = a1; a1 = a2; b0 = b1; b1 = b2;
        if (kk < 30) {
            a2 = *(const int4*)(arow + (kk + 3) * 32);
            b2 = *(const int2*)(brow + (kk + 3) * 32);
        }
        s8v af = *(const s8v*)(At + (wv * 16 + l16) * 32 + quad * 8);
#pragma unroll
        for (int ng = 0; ng < 2; ++ng) {
            s8v bf = *(const s8v*)(Bt + (ng * 16 + l16) * 32 + quad * 8);
            acc[ng] = __builtin_amdgcn_mfma_f32_16x16x32_bf16(af, bf, acc[ng], 0, 0, 0);
        }
        __syncthreads();
    }
#pragma unroll
    for (int ng = 0; ng < 2; ++ng) {
        int col = n0 + ng * 16 + l16;
#pragma unroll
        for (int rr = 0; rr < 4; ++rr) {
            int row = wv * 16 + quad * 4 + rr;   // t
            if (row < T_) out[(size_t)(b * T_ + row) * D_ + col] = acc[ng][rr];
        }
    }
}

extern "C" void kernel_launch(void* const* d_in, const int* in_sizes, int n_in,
                              void* d_out, int out_size, void* d_ws, size_t ws_size,
                              hipStream_t stream)
{
    (void)in_sizes; (void)n_in; (void)out_size; (void)ws_size;
    const float* source          = (const float*)d_in[0];
    const float* src_bank        = (const float*)d_in[1];
    const int*   src_lengths     = (const int*)d_in[2];
    const float* qa_sent_bank    = (const float*)d_in[3];
    /* d_in[4] qa_sent_lengths unused (matches reference) */
    const float* qa_word_bank    = (const float*)d_in[5];
    const int*   qa_word_lengths = (const int*)d_in[6];
    const float* Wq_word = (const float*)d_in[7];
    const float* bq_word = (const float*)d_in[8];
    const float* Uc_word = (const float*)d_in[9];
    const float* v_word  = (const float*)d_in[10];
    const float* Wq_sent = (const float*)d_in[11];
    const float* bq_sent = (const float*)d_in[12];
    const float* Uc_sent = (const float*)d_in[13];
    const float* v_sent  = (const float*)d_in[14];
    const float* Wq_pass = (const float*)d_in[15];
    const float* bq_pass = (const float*)d_in[16];
    const float* Uc_pass = (const float*)d_in[17];
    const float* v_pass  = (const float*)d_in[18];

    float* wsf = (float*)d_ws;
    ushort_t* Pb  = (ushort_t*)((char*)d_ws + P_BYTE_OFF);
    ushort_t* mt  = (ushort_t*)((char*)d_ws + MT_BYTE_OFF);
    ushort_t* wt  = (ushort_t*)((char*)d_ws + WT_BYTE_OFF);
    float* out = (float*)d_out;

    // Wt slot order must match k1 segment order:
    // 0:Wq_word 1:Wq_sent 2:Wq_pass 3:Uc_word 4:Uc_pass 5:Uc_sent
    k0f_transpose<<<dim3(3648), dim3(256), 0, stream>>>(
        Wq_word, Wq_sent, Wq_pass, Uc_word, Uc_pass, Uc_sent,
        src_bank, qa_word_bank, wt, mt);
    k1_gemm<<<dim3(624), dim3(256), 0, stream>>>(
        source, src_bank, qa_sent_bank, qa_word_bank, wt,
        bq_word, bq_sent, bq_pass, wsf);
    k2_scores<<<dim3(5280), dim3(256), 0, stream>>>(
        v_word, v_sent, v_pass, src_lengths, qa_word_lengths, wsf);
    k3a_softmax<<<dim3(200), dim3(256), 0, stream>>>(src_lengths, qa_word_lengths, wsf, Pb);
    k3c_gemm<<<dim3(16, 4), dim3(256), 0, stream>>>(Pb, mt, out);
}